// Round 6
// baseline (634.583 us; speedup 1.0000x reference)
//
#include <hip/hip_runtime.h>
#include <cstdint>
#include <cstddef>

// ---------------- types ----------------
using v8s  = __attribute__((ext_vector_type(8))) short;   // 8 x bf16 (4 VGPR)
using v4f  = __attribute__((ext_vector_type(4))) float;   // MFMA accumulator

#define MFMA(a, b, c) __builtin_amdgcn_mfma_f32_16x16x32_bf16(a, b, c, 0, 0, 0)

__device__ __forceinline__ unsigned short f2bf(float f) {
    unsigned int u = __float_as_uint(f);
    unsigned int r = (u + 0x7fffu + ((u >> 16) & 1u)) >> 16;   // RNE, finite inputs
    return (unsigned short)r;
}

// ---------------- cast x -> bf16 ----------------
__global__ __launch_bounds__(256) void cast_x_kernel(const float* __restrict__ x,
                                                     unsigned short* __restrict__ xb) {
    size_t i = ((size_t)blockIdx.x * 256 + threadIdx.x) * 8;
    float4 a = *reinterpret_cast<const float4*>(x + i);
    float4 b = *reinterpret_cast<const float4*>(x + i + 4);
    union { unsigned short u[8]; v8s v; } o;
    o.u[0] = f2bf(a.x); o.u[1] = f2bf(a.y); o.u[2] = f2bf(a.z); o.u[3] = f2bf(a.w);
    o.u[4] = f2bf(b.x); o.u[5] = f2bf(b.y); o.u[6] = f2bf(b.z); o.u[7] = f2bf(b.w);
    *reinterpret_cast<v8s*>(xb + i) = o.v;
}

// ---------------- W [K][N] fp32 -> Wt [N][K] bf16 ----------------
__global__ __launch_bounds__(256) void transpose_w_kernel(const float* __restrict__ W,
                                                          unsigned short* __restrict__ Wt,
                                                          int Kd, int Nd) {
    __shared__ float tile[32][33];
    int tx = threadIdx.x, ty = threadIdx.y;
    int n0 = blockIdx.x * 32, k0 = blockIdx.y * 32;
#pragma unroll
    for (int i = 0; i < 4; ++i)
        tile[ty + i * 8][tx] = W[(size_t)(k0 + ty + i * 8) * Nd + (n0 + tx)];
    __syncthreads();
#pragma unroll
    for (int i = 0; i < 4; ++i)
        Wt[(size_t)(n0 + ty + i * 8) * Kd + (k0 + tx)] = f2bf(tile[tx][ty + i * 8]);
}

// ---------------- GEMM: C[M,N] = A[M,K=1024] * Bt[N,K=1024]^T ----------------
// EPI 0: qkv scatter epilogue (q scaled 0.125, v transposed), EPI 1: fp32 out + bias
template <int EPI>
__global__ __launch_bounds__(256, 2) void gemm_bt(const unsigned short* __restrict__ A,
                                                  const unsigned short* __restrict__ Bt,
                                                  const float* __restrict__ bias,
                                                  unsigned short* __restrict__ outq,
                                                  unsigned short* __restrict__ outk,
                                                  unsigned short* __restrict__ outv,
                                                  float* __restrict__ outf) {
    __shared__ unsigned short sA[128 * 64];
    __shared__ unsigned short sB[128 * 64];
    const int tid = threadIdx.x;
    const int lane = tid & 63, wid = tid >> 6;
    const int lr = lane & 15, lg = lane >> 4;
    const int m0 = blockIdx.x * 128, n0 = blockIdx.y * 128;
    const int wr = wid >> 1, wc = wid & 1;

    v4f acc[4][4] = {};

    // staging geometry: logical tile byte o = j*4096 + tid*16; LDS gets global data
    // from the XOR-swizzled column so that swizzled ds_reads see logical data.
    int srow[4], scol[4];
#pragma unroll
    for (int j = 0; j < 4; ++j) {
        int o = j * 4096 + tid * 16;
        int row = o >> 7, cb = o & 127;
        srow[j] = row;
        scol[j] = (cb ^ ((row & 7) << 4)) >> 1;   // halfword offset within row
    }

    for (int kt = 0; kt < 16; ++kt) {
        __syncthreads();
#pragma unroll
        for (int j = 0; j < 4; ++j) {
            const unsigned short* ga = A + (size_t)(m0 + srow[j]) * 1024 + kt * 64 + scol[j];
            __builtin_amdgcn_global_load_lds(
                (const __attribute__((address_space(1))) void*)ga,
                (__attribute__((address_space(3))) void*)((char*)sA + j * 4096 + wid * 1024),
                16, 0, 0);
            const unsigned short* gb = Bt + (size_t)(n0 + srow[j]) * 1024 + kt * 64 + scol[j];
            __builtin_amdgcn_global_load_lds(
                (const __attribute__((address_space(1))) void*)gb,
                (__attribute__((address_space(3))) void*)((char*)sB + j * 4096 + wid * 1024),
                16, 0, 0);
        }
        __syncthreads();

        v8s af[4][2], bf[4][2];
#pragma unroll
        for (int m = 0; m < 4; ++m) {
            int row = wr * 64 + m * 16 + lr;
#pragma unroll
            for (int kk = 0; kk < 2; ++kk) {
                int c = (kk * 64 + lg * 16) ^ ((row & 7) << 4);
                af[m][kk] = *reinterpret_cast<const v8s*>((const char*)sA + row * 128 + c);
            }
        }
#pragma unroll
        for (int n = 0; n < 4; ++n) {
            int row = wc * 64 + n * 16 + lr;
#pragma unroll
            for (int kk = 0; kk < 2; ++kk) {
                int c = (kk * 64 + lg * 16) ^ ((row & 7) << 4);
                bf[n][kk] = *reinterpret_cast<const v8s*>((const char*)sB + row * 128 + c);
            }
        }
#pragma unroll
        for (int m = 0; m < 4; ++m)
#pragma unroll
            for (int n = 0; n < 4; ++n) {
                acc[m][n] = MFMA(af[m][0], bf[n][0], acc[m][n]);
                acc[m][n] = MFMA(af[m][1], bf[n][1], acc[m][n]);
            }
    }

    // epilogue: C element (row=(lane>>4)*4+reg, col=lane&15) per m89-verified layout
#pragma unroll
    for (int m = 0; m < 4; ++m) {
        int rowb = m0 + wr * 64 + m * 16 + lg * 4;
#pragma unroll
        for (int n = 0; n < 4; ++n) {
            int gn = n0 + wc * 64 + n * 16 + lr;
            float bs = bias[gn];
            if (EPI == 0) {
                int which = gn >> 10, e = gn & 1023;
                int h = e >> 6, d = e & 63;
#pragma unroll
                for (int r = 0; r < 4; ++r) {
                    int grow = rowb + r;
                    int b = grow >> 11, t = grow & 2047;
                    size_t bh = (size_t)(b * 16 + h);
                    float v = acc[m][n][r] + bs;
                    if (which == 0)
                        outq[(bh * 2048 + t) * 64 + d] = f2bf(v * 0.125f);
                    else if (which == 1)
                        outk[(bh * 2048 + t) * 64 + d] = f2bf(v);
                    else
                        outv[(bh * 64 + d) * 2048 + t] = f2bf(v);
                }
            } else {
#pragma unroll
                for (int r = 0; r < 4; ++r)
                    outf[(size_t)(rowb + r) * 1024 + gn] = acc[m][n][r] + bs;
            }
        }
    }
}

// ---------------- flash attention (causal), hd=64, KVBLK=32 ----------------
// qb/kb: [BH][T][64] bf16 (q pre-scaled by 0.125), vT: [BH][64][T] bf16
// yb out: [B][T][E] bf16
__global__ __launch_bounds__(256, 2) void attn_kernel(const unsigned short* __restrict__ qb,
                                                      const unsigned short* __restrict__ kb,
                                                      const unsigned short* __restrict__ vT,
                                                      unsigned short* __restrict__ yb) {
    // per-wave P tile, stride 40 halfwords (2-way bank aliasing = free, m136).
    // No __syncthreads needed anywhere: each wave touches only pbuf[wid];
    // intra-wave ds_write->ds_read ordering is the compiler's lgkmcnt job.
    __shared__ unsigned short pbuf[4][16 * 40];
    const int tid = threadIdx.x;
    const int lane = tid & 63, wid = tid >> 6;
    const int lr = lane & 15, lg = lane >> 4;
    const int qt = blockIdx.x, bh = blockIdx.y;

    const unsigned short* Q  = qb + (size_t)bh * 2048 * 64;
    const unsigned short* Kp = kb + (size_t)bh * 2048 * 64;
    const unsigned short* Vt = vT + (size_t)bh * 64 * 2048;

    const int q0 = qt * 64 + wid * 16;
    v8s qf0 = *reinterpret_cast<const v8s*>(Q + (size_t)(q0 + lr) * 64 + lg * 8);
    v8s qf1 = *reinterpret_cast<const v8s*>(Q + (size_t)(q0 + lr) * 64 + 32 + lg * 8);

    float mrow[4], lrow[4];
    v4f yacc[4] = {};
#pragma unroll
    for (int r = 0; r < 4; ++r) { mrow[r] = -1e30f; lrow[r] = 0.f; }

    const int ntiles = (qt + 1) * 2;
    for (int kt = 0; kt < ntiles; ++kt) {
        const int kv0 = kt * 32;
        v4f sacc[2] = {};
#pragma unroll
        for (int j = 0; j < 2; ++j) {
            const unsigned short* kp = Kp + (size_t)(kv0 + j * 16 + lr) * 64 + lg * 8;
            v8s kf0 = *reinterpret_cast<const v8s*>(kp);
            v8s kf1 = *reinterpret_cast<const v8s*>(kp + 32);
            sacc[j] = MFMA(qf0, kf0, sacc[j]);
            sacc[j] = MFMA(qf1, kf1, sacc[j]);
        }
        // causal mask
        const int qrb = q0 + lg * 4;
#pragma unroll
        for (int j = 0; j < 2; ++j) {
            int kv = kv0 + j * 16 + lr;
#pragma unroll
            for (int r = 0; r < 4; ++r)
                if (kv > qrb + r) sacc[j][r] = -1e30f;
        }
        // online softmax (row-reduce over the 16-lane column group)
        float sc[4];
#pragma unroll
        for (int r = 0; r < 4; ++r) {
            float tmax = fmaxf(sacc[0][r], sacc[1][r]);
#pragma unroll
            for (int off = 1; off < 16; off <<= 1)
                tmax = fmaxf(tmax, __shfl_xor(tmax, off, 64));
            float newm = fmaxf(mrow[r], tmax);
            sc[r] = __expf(mrow[r] - newm);
            mrow[r] = newm;
            float p0 = __expf(sacc[0][r] - newm);
            float p1 = __expf(sacc[1][r] - newm);
            sacc[0][r] = p0; sacc[1][r] = p1;
            float ps = p0 + p1;
#pragma unroll
            for (int off = 1; off < 16; off <<= 1)
                ps += __shfl_xor(ps, off, 64);
            lrow[r] = lrow[r] * sc[r] + ps;
        }
#pragma unroll
        for (int n = 0; n < 4; ++n)
#pragma unroll
            for (int r = 0; r < 4; ++r) yacc[n][r] *= sc[r];

        // P (16q x 32kv) -> per-wave LDS slice in A-fragment layout
        unsigned short* pw = pbuf[wid];
#pragma unroll
        for (int j = 0; j < 2; ++j)
#pragma unroll
            for (int r = 0; r < 4; ++r)
                pw[(lg * 4 + r) * 40 + j * 16 + lr] = f2bf(sacc[j][r]);
        v8s pf = *reinterpret_cast<const v8s*>(pbuf[wid] + lr * 40 + lg * 8);
#pragma unroll
        for (int n = 0; n < 4; ++n) {
            v8s vf = *reinterpret_cast<const v8s*>(Vt + (size_t)(n * 16 + lr) * 2048 + kv0 + lg * 8);
            yacc[n] = MFMA(pf, vf, yacc[n]);
        }
    }

    const int b = bh >> 4, h = bh & 15;
#pragma unroll
    for (int r = 0; r < 4; ++r) {
        float inv = 1.0f / lrow[r];
        int t = q0 + lg * 4 + r;
#pragma unroll
        for (int n = 0; n < 4; ++n)
            yb[((size_t)b * 2048 + t) * 1024 + h * 64 + n * 16 + lr] = f2bf(yacc[n][r] * inv);
    }
}

// ---------------- launch ----------------
extern "C" void kernel_launch(void* const* d_in, const int* in_sizes, int n_in,
                              void* d_out, int out_size, void* d_ws, size_t ws_size,
                              hipStream_t stream) {
    const float* x     = (const float*)d_in[0];
    const float* W_qkv = (const float*)d_in[1];
    const float* b_qkv = (const float*)d_in[2];
    const float* W_out = (const float*)d_in[3];
    const float* b_out = (const float*)d_in[4];
    float* out = (float*)d_out;

    if (ws_size < (72ull << 20)) return;   // clean fail instead of corruption

    char* ws = (char*)d_ws;
    unsigned short* xb_yb = (unsigned short*)(ws);                  // 16 MB (xb, then reused as yb)
    unsigned short* qbf   = (unsigned short*)(ws + (16ull << 20));  // 16 MB
    unsigned short* kbf   = (unsigned short*)(ws + (32ull << 20));  // 16 MB
    unsigned short* vTb   = (unsigned short*)(ws + (48ull << 20));  // 16 MB
    unsigned short* wqkvT = (unsigned short*)(ws + (64ull << 20));  // 6 MB
    unsigned short* woutT = (unsigned short*)(ws + (70ull << 20));  // 2 MB

    cast_x_kernel<<<dim3(4096), dim3(256), 0, stream>>>(x, xb_yb);
    transpose_w_kernel<<<dim3(96, 32), dim3(32, 8), 0, stream>>>(W_qkv, wqkvT, 1024, 3072);
    transpose_w_kernel<<<dim3(32, 32), dim3(32, 8), 0, stream>>>(W_out, woutT, 1024, 1024);
    gemm_bt<0><<<dim3(64, 24), dim3(256), 0, stream>>>(xb_yb, wqkvT, b_qkv, qbf, kbf, vTb, nullptr);
    attn_kernel<<<dim3(32, 64), dim3(256), 0, stream>>>(qbf, kbf, vTb, xb_yb);
    gemm_bt<1><<<dim3(64, 8), dim3(256), 0, stream>>>(xb_yb, woutT, b_out, nullptr, nullptr, nullptr, out);
}

// Round 8
// 345.067 us; speedup vs baseline: 1.8390x; 1.8390x over previous
//
#include <hip/hip_runtime.h>
#include <cstdint>
#include <cstddef>

// ---------------- types ----------------
using v8s  = __attribute__((ext_vector_type(8))) short;   // 8 x bf16 (4 VGPR)
using v4f  = __attribute__((ext_vector_type(4))) float;   // MFMA accumulator

#define MFMA(a, b, c) __builtin_amdgcn_mfma_f32_16x16x32_bf16(a, b, c, 0, 0, 0)
#define AS1(p) (const __attribute__((address_space(1))) void*)(p)
#define AS3(p) (__attribute__((address_space(3))) void*)(p)

__device__ __forceinline__ unsigned short f2bf(float f) {
    unsigned int u = __float_as_uint(f);
    unsigned int r = (u + 0x7fffu + ((u >> 16) & 1u)) >> 16;   // RNE, finite inputs
    return (unsigned short)r;
}

// ---------------- cast x -> bf16 ----------------
__global__ __launch_bounds__(256) void cast_x_kernel(const float* __restrict__ x,
                                                     unsigned short* __restrict__ xb) {
    size_t i = ((size_t)blockIdx.x * 256 + threadIdx.x) * 8;
    float4 a = *reinterpret_cast<const float4*>(x + i);
    float4 b = *reinterpret_cast<const float4*>(x + i + 4);
    union { unsigned short u[8]; v8s v; } o;
    o.u[0] = f2bf(a.x); o.u[1] = f2bf(a.y); o.u[2] = f2bf(a.z); o.u[3] = f2bf(a.w);
    o.u[4] = f2bf(b.x); o.u[5] = f2bf(b.y); o.u[6] = f2bf(b.z); o.u[7] = f2bf(b.w);
    *reinterpret_cast<v8s*>(xb + i) = o.v;
}

// ---------------- W [K][N] fp32 -> Wt [N][K] bf16 ----------------
__global__ __launch_bounds__(256) void transpose_w_kernel(const float* __restrict__ W,
                                                          unsigned short* __restrict__ Wt,
                                                          int Kd, int Nd) {
    __shared__ float tile[32][33];
    int tx = threadIdx.x, ty = threadIdx.y;
    int n0 = blockIdx.x * 32, k0 = blockIdx.y * 32;
#pragma unroll
    for (int i = 0; i < 4; ++i)
        tile[ty + i * 8][tx] = W[(size_t)(k0 + ty + i * 8) * Nd + (n0 + tx)];
    __syncthreads();
#pragma unroll
    for (int i = 0; i < 4; ++i)
        Wt[(size_t)(n0 + ty + i * 8) * Kd + (k0 + tx)] = f2bf(tile[tx][ty + i * 8]);
}

// ---------------- GEMM: C[M,N] = A[M,K=1024] * Bt[N,K=1024]^T ----------------
// EPI 0: qkv scatter epilogue (q scaled 0.125, v transposed), EPI 1: fp32 out + bias
template <int EPI>
__global__ __launch_bounds__(256, 2) void gemm_bt(const unsigned short* __restrict__ A,
                                                  const unsigned short* __restrict__ Bt,
                                                  const float* __restrict__ bias,
                                                  unsigned short* __restrict__ outq,
                                                  unsigned short* __restrict__ outk,
                                                  unsigned short* __restrict__ outv,
                                                  float* __restrict__ outf) {
    __shared__ unsigned short sA[128 * 64];
    __shared__ unsigned short sB[128 * 64];
    const int tid = threadIdx.x;
    const int lane = tid & 63, wid = tid >> 6;
    const int lr = lane & 15, lg = lane >> 4;
    const int m0 = blockIdx.x * 128, n0 = blockIdx.y * 128;
    const int wr = wid >> 1, wc = wid & 1;

    v4f acc[4][4] = {};

    int srow[4], scol[4];
#pragma unroll
    for (int j = 0; j < 4; ++j) {
        int o = j * 4096 + tid * 16;
        int row = o >> 7, cb = o & 127;
        srow[j] = row;
        scol[j] = (cb ^ ((row & 7) << 4)) >> 1;   // halfword offset within row
    }

    for (int kt = 0; kt < 16; ++kt) {
        __syncthreads();
#pragma unroll
        for (int j = 0; j < 4; ++j) {
            const unsigned short* ga = A + (size_t)(m0 + srow[j]) * 1024 + kt * 64 + scol[j];
            __builtin_amdgcn_global_load_lds(AS1(ga), AS3((char*)sA + j * 4096 + wid * 1024), 16, 0, 0);
            const unsigned short* gb = Bt + (size_t)(n0 + srow[j]) * 1024 + kt * 64 + scol[j];
            __builtin_amdgcn_global_load_lds(AS1(gb), AS3((char*)sB + j * 4096 + wid * 1024), 16, 0, 0);
        }
        __syncthreads();

        v8s af[4][2], bf[4][2];
#pragma unroll
        for (int m = 0; m < 4; ++m) {
            int row = wr * 64 + m * 16 + lr;
#pragma unroll
            for (int kk = 0; kk < 2; ++kk) {
                int c = (kk * 64 + lg * 16) ^ ((row & 7) << 4);
                af[m][kk] = *reinterpret_cast<const v8s*>((const char*)sA + row * 128 + c);
            }
        }
#pragma unroll
        for (int n = 0; n < 4; ++n) {
            int row = wc * 64 + n * 16 + lr;
#pragma unroll
            for (int kk = 0; kk < 2; ++kk) {
                int c = (kk * 64 + lg * 16) ^ ((row & 7) << 4);
                bf[n][kk] = *reinterpret_cast<const v8s*>((const char*)sB + row * 128 + c);
            }
        }
#pragma unroll
        for (int m = 0; m < 4; ++m)
#pragma unroll
            for (int n = 0; n < 4; ++n) {
                acc[m][n] = MFMA(af[m][0], bf[n][0], acc[m][n]);
                acc[m][n] = MFMA(af[m][1], bf[n][1], acc[m][n]);
            }
    }

    // epilogue: C element (row=(lane>>4)*4+reg, col=lane&15) per m89-verified layout
#pragma unroll
    for (int m = 0; m < 4; ++m) {
        int rowb = m0 + wr * 64 + m * 16 + lg * 4;
#pragma unroll
        for (int n = 0; n < 4; ++n) {
            int gn = n0 + wc * 64 + n * 16 + lr;
            float bs = bias[gn];
            if (EPI == 0) {
                int which = gn >> 10, e = gn & 1023;
                int h = e >> 6, d = e & 63;
#pragma unroll
                for (int r = 0; r < 4; ++r) {
                    int grow = rowb + r;
                    int b = grow >> 11, t = grow & 2047;
                    size_t bh = (size_t)(b * 16 + h);
                    float v = acc[m][n][r] + bs;
                    if (which == 0)
                        outq[(bh * 2048 + t) * 64 + d] = f2bf(v * 0.125f);
                    else if (which == 1)
                        outk[(bh * 2048 + t) * 64 + d] = f2bf(v);
                    else
                        outv[(bh * 64 + d) * 2048 + t] = f2bf(v);
                }
            } else {
#pragma unroll
                for (int r = 0; r < 4; ++r)
                    outf[(size_t)(rowb + r) * 1024 + gn] = acc[m][n][r] + bs;
            }
        }
    }
}

// ---------------- flash attention (causal), hd=64, KVBLK=64, LDS-staged K/V ----------------
// qb/kb: [BH][T][64] bf16 (q pre-scaled by 0.125), vT: [BH][64][T] bf16; yb: [B][T][E] bf16
// 1D grid 2048; XCD-clustered (8 heads per XCD -> K/V fits one 4MB L2) + LPT (long qt first).
__global__ __launch_bounds__(256, 2) void attn_kernel(const unsigned short* __restrict__ qb,
                                                      const unsigned short* __restrict__ kb,
                                                      const unsigned short* __restrict__ vT,
                                                      unsigned short* __restrict__ yb) {
    __shared__ unsigned short sK[2][64 * 64];   // [kv][d], XOR-swizzled rows, dbuf
    __shared__ unsigned short sV[2][64 * 64];   // [d][kv], XOR-swizzled rows, dbuf
    __shared__ unsigned short pbuf[4][16 * 72]; // per-wave P tile, stride 72 hw

    const int tid = threadIdx.x;
    const int lane = tid & 63, wid = tid >> 6;
    const int lr = lane & 15, lg = lane >> 4;

    // XCD-clustering swizzle (m157, bijective since 2048%8==0) + LPT qt order
    const int bid = blockIdx.x;
    const int o = (bid & 7) * 256 + (bid >> 3);
    const int bh = o >> 5;
    const int qt = 31 - (o & 31);

    const unsigned short* Q  = qb + (size_t)bh * 2048 * 64;
    const unsigned short* Kp = kb + (size_t)bh * 2048 * 64;
    const unsigned short* Vt = vT + (size_t)bh * 64 * 2048;

    const int q0 = qt * 64 + wid * 16;
    v8s qf0 = *reinterpret_cast<const v8s*>(Q + (size_t)(q0 + lr) * 64 + lg * 8);
    v8s qf1 = *reinterpret_cast<const v8s*>(Q + (size_t)(q0 + lr) * 64 + 32 + lg * 8);

    // staging geometry: per buffer K(8KB)/V(8KB), 256 thr x 16B x 2 iters each.
    // logical byte os -> row=os>>7, colb=os&127; source col pre-swizzled (rule 21).
    int strow[2], stcol[2];
#pragma unroll
    for (int it = 0; it < 2; ++it) {
        int os = it * 4096 + tid * 16;
        int row = os >> 7, cb = os & 127;
        strow[it] = row;
        stcol[it] = (cb ^ ((row & 7) << 4)) >> 1;
    }

    auto stage = [&](int buf, int kv0) {
#pragma unroll
        for (int it = 0; it < 2; ++it) {
            int os = it * 4096 + tid * 16;
            __builtin_amdgcn_global_load_lds(
                AS1(Kp + (size_t)(kv0 + strow[it]) * 64 + stcol[it]),
                AS3((char*)sK[buf] + os), 16, 0, 0);
            __builtin_amdgcn_global_load_lds(
                AS1(Vt + (size_t)strow[it] * 2048 + kv0 + stcol[it]),
                AS3((char*)sV[buf] + os), 16, 0, 0);
        }
    };

    float mrow[4], lrow[4];
    v4f yacc[4] = {};
#pragma unroll
    for (int r = 0; r < 4; ++r) { mrow[r] = -1e30f; lrow[r] = 0.f; }

    stage(0, 0);
    int cur = 0;
    for (int kt = 0; kt <= qt; ++kt) {
        __syncthreads();                       // buf[cur] staged (vmcnt drained at barrier)
        if (kt < qt) stage(cur ^ 1, (kt + 1) * 64);

        // QK^T: S[q=lg*4+r][kv=j*16+lr], K from swizzled LDS
        v4f sacc[4] = {};
#pragma unroll
        for (int j = 0; j < 4; ++j) {
            int row = j * 16 + lr;
            int sw = (row & 7) << 4;
            v8s kf0 = *reinterpret_cast<const v8s*>((const char*)sK[cur] + row * 128 + ((lg * 16) ^ sw));
            v8s kf1 = *reinterpret_cast<const v8s*>((const char*)sK[cur] + row * 128 + ((64 + lg * 16) ^ sw));
            sacc[j] = MFMA(qf0, kf0, sacc[j]);
            sacc[j] = MFMA(qf1, kf1, sacc[j]);
        }

        if (kt == qt) {                        // only the diagonal tile needs masking
            const int qrb = q0 + lg * 4;
            const int kv0 = kt * 64;
#pragma unroll
            for (int j = 0; j < 4; ++j) {
                int kv = kv0 + j * 16 + lr;
#pragma unroll
                for (int r = 0; r < 4; ++r)
                    if (kv > qrb + r) sacc[j][r] = -1e30f;
            }
        }

        // online softmax (reduce over kv: 4 regs + 16-lane shuffle group)
        float sc[4];
#pragma unroll
        for (int r = 0; r < 4; ++r) {
            float tmax = fmaxf(fmaxf(sacc[0][r], sacc[1][r]), fmaxf(sacc[2][r], sacc[3][r]));
#pragma unroll
            for (int off = 1; off < 16; off <<= 1)
                tmax = fmaxf(tmax, __shfl_xor(tmax, off, 64));
            float newm = fmaxf(mrow[r], tmax);
            sc[r] = __expf(mrow[r] - newm);
            mrow[r] = newm;
            float ps = 0.f;
#pragma unroll
            for (int j = 0; j < 4; ++j) {
                float p = __expf(sacc[j][r] - newm);
                sacc[j][r] = p;
                ps += p;
            }
#pragma unroll
            for (int off = 1; off < 16; off <<= 1)
                ps += __shfl_xor(ps, off, 64);
            lrow[r] = lrow[r] * sc[r] + ps;
        }
#pragma unroll
        for (int n = 0; n < 4; ++n)
#pragma unroll
            for (int r = 0; r < 4; ++r) yacc[n][r] *= sc[r];

        // P (16q x 64kv) -> per-wave LDS slice in A-fragment layout
        unsigned short* pw = pbuf[wid];
#pragma unroll
        for (int j = 0; j < 4; ++j)
#pragma unroll
            for (int r = 0; r < 4; ++r)
                pw[(lg * 4 + r) * 72 + j * 16 + lr] = f2bf(sacc[j][r]);

        v8s pf0 = *reinterpret_cast<const v8s*>(pw + lr * 72 + lg * 8);
        v8s pf1 = *reinterpret_cast<const v8s*>(pw + lr * 72 + 32 + lg * 8);
#pragma unroll
        for (int n = 0; n < 4; ++n) {
            int row = n * 16 + lr;
            int sw = (row & 7) << 4;
            v8s vf0 = *reinterpret_cast<const v8s*>((const char*)sV[cur] + row * 128 + ((lg * 16) ^ sw));
            v8s vf1 = *reinterpret_cast<const v8s*>((const char*)sV[cur] + row * 128 + ((64 + lg * 16) ^ sw));
            yacc[n] = MFMA(pf0, vf0, yacc[n]);
            yacc[n] = MFMA(pf1, vf1, yacc[n]);
        }
        cur ^= 1;
    }

    const int b = bh >> 4, h = bh & 15;
#pragma unroll
    for (int r = 0; r < 4; ++r) {
        float inv = 1.0f / lrow[r];
        int t = q0 + lg * 4 + r;
#pragma unroll
        for (int n = 0; n < 4; ++n)
            yb[((size_t)b * 2048 + t) * 1024 + h * 64 + n * 16 + lr] = f2bf(yacc[n][r] * inv);
    }
}

// ---------------- launch ----------------
extern "C" void kernel_launch(void* const* d_in, const int* in_sizes, int n_in,
                              void* d_out, int out_size, void* d_ws, size_t ws_size,
                              hipStream_t stream) {
    const float* x     = (const float*)d_in[0];
    const float* W_qkv = (const float*)d_in[1];
    const float* b_qkv = (const float*)d_in[2];
    const float* W_out = (const float*)d_in[3];
    const float* b_out = (const float*)d_in[4];
    float* out = (float*)d_out;

    if (ws_size < (72ull << 20)) return;   // clean fail instead of corruption

    char* ws = (char*)d_ws;
    unsigned short* xb_yb = (unsigned short*)(ws);                  // 16 MB (xb, then reused as yb)
    unsigned short* qbf   = (unsigned short*)(ws + (16ull << 20));  // 16 MB
    unsigned short* kbf   = (unsigned short*)(ws + (32ull << 20));  // 16 MB
    unsigned short* vTb   = (unsigned short*)(ws + (48ull << 20));  // 16 MB
    unsigned short* wqkvT = (unsigned short*)(ws + (64ull << 20));  // 6 MB
    unsigned short* woutT = (unsigned short*)(ws + (70ull << 20));  // 2 MB

    cast_x_kernel<<<dim3(4096), dim3(256), 0, stream>>>(x, xb_yb);
    transpose_w_kernel<<<dim3(96, 32), dim3(32, 8), 0, stream>>>(W_qkv, wqkvT, 1024, 3072);
    transpose_w_kernel<<<dim3(32, 32), dim3(32, 8), 0, stream>>>(W_out, woutT, 1024, 1024);
    gemm_bt<0><<<dim3(64, 24), dim3(256), 0, stream>>>(xb_yb, wqkvT, b_qkv, qbf, kbf, vTb, nullptr);
    attn_kernel<<<dim3(2048), dim3(256), 0, stream>>>(qbf, kbf, vTb, xb_yb);
    gemm_bt<1><<<dim3(64, 8), dim3(256), 0, stream>>>(xb_yb, woutT, b_out, nullptr, nullptr, nullptr, out);
}

// Round 9
// 319.298 us; speedup vs baseline: 1.9874x; 1.0807x over previous
//
#include <hip/hip_runtime.h>
#include <cstdint>
#include <cstddef>

// ---------------- types ----------------
using v8s  = __attribute__((ext_vector_type(8))) short;   // 8 x bf16 (4 VGPR)
using v4f  = __attribute__((ext_vector_type(4))) float;   // MFMA accumulator

#define MFMA(a, b, c) __builtin_amdgcn_mfma_f32_16x16x32_bf16(a, b, c, 0, 0, 0)
#define AS1(p) (const __attribute__((address_space(1))) void*)(p)
#define AS3(p) (__attribute__((address_space(3))) void*)(p)

__device__ __forceinline__ unsigned short f2bf(float f) {
    unsigned int u = __float_as_uint(f);
    unsigned int r = (u + 0x7fffu + ((u >> 16) & 1u)) >> 16;   // RNE, finite inputs
    return (unsigned short)r;
}

// ---------------- cast x -> bf16 ----------------
__global__ __launch_bounds__(256) void cast_x_kernel(const float* __restrict__ x,
                                                     unsigned short* __restrict__ xb) {
    size_t i = ((size_t)blockIdx.x * 256 + threadIdx.x) * 8;
    float4 a = *reinterpret_cast<const float4*>(x + i);
    float4 b = *reinterpret_cast<const float4*>(x + i + 4);
    union { unsigned short u[8]; v8s v; } o;
    o.u[0] = f2bf(a.x); o.u[1] = f2bf(a.y); o.u[2] = f2bf(a.z); o.u[3] = f2bf(a.w);
    o.u[4] = f2bf(b.x); o.u[5] = f2bf(b.y); o.u[6] = f2bf(b.z); o.u[7] = f2bf(b.w);
    *reinterpret_cast<v8s*>(xb + i) = o.v;
}

// ---------------- W [K][N] fp32 -> Wt [N][K] bf16 ----------------
__global__ __launch_bounds__(256) void transpose_w_kernel(const float* __restrict__ W,
                                                          unsigned short* __restrict__ Wt,
                                                          int Kd, int Nd) {
    __shared__ float tile[32][33];
    int tx = threadIdx.x, ty = threadIdx.y;
    int n0 = blockIdx.x * 32, k0 = blockIdx.y * 32;
#pragma unroll
    for (int i = 0; i < 4; ++i)
        tile[ty + i * 8][tx] = W[(size_t)(k0 + ty + i * 8) * Nd + (n0 + tx)];
    __syncthreads();
#pragma unroll
    for (int i = 0; i < 4; ++i)
        Wt[(size_t)(n0 + ty + i * 8) * Kd + (k0 + tx)] = f2bf(tile[tx][ty + i * 8]);
}

// ---------------- GEMM: C[M,N] = A[M,K=1024] * Bt[N,K=1024]^T ----------------
// EPI 0: qkv scatter epilogue (q scaled 0.125, v transposed), EPI 1: fp32 out + bias
// launch_bounds(256,3): 3 blocks/CU (LDS 32KB allows 5; VGPR cap 170) for wave-overlap (m114).
template <int EPI>
__global__ __launch_bounds__(256, 3) void gemm_bt(const unsigned short* __restrict__ A,
                                                  const unsigned short* __restrict__ Bt,
                                                  const float* __restrict__ bias,
                                                  unsigned short* __restrict__ outq,
                                                  unsigned short* __restrict__ outk,
                                                  unsigned short* __restrict__ outv,
                                                  float* __restrict__ outf) {
    __shared__ unsigned short sA[128 * 64];
    __shared__ unsigned short sB[128 * 64];
    const int tid = threadIdx.x;
    const int lane = tid & 63, wid = tid >> 6;
    const int lr = lane & 15, lg = lane >> 4;
    const int m0 = blockIdx.x * 128, n0 = blockIdx.y * 128;
    const int wr = wid >> 1, wc = wid & 1;

    v4f acc[4][4] = {};

    int srow[4], scol[4];
#pragma unroll
    for (int j = 0; j < 4; ++j) {
        int o = j * 4096 + tid * 16;
        int row = o >> 7, cb = o & 127;
        srow[j] = row;
        scol[j] = (cb ^ ((row & 7) << 4)) >> 1;   // halfword offset within row
    }

    for (int kt = 0; kt < 16; ++kt) {
        __syncthreads();
#pragma unroll
        for (int j = 0; j < 4; ++j) {
            const unsigned short* ga = A + (size_t)(m0 + srow[j]) * 1024 + kt * 64 + scol[j];
            __builtin_amdgcn_global_load_lds(AS1(ga), AS3((char*)sA + j * 4096 + wid * 1024), 16, 0, 0);
            const unsigned short* gb = Bt + (size_t)(n0 + srow[j]) * 1024 + kt * 64 + scol[j];
            __builtin_amdgcn_global_load_lds(AS1(gb), AS3((char*)sB + j * 4096 + wid * 1024), 16, 0, 0);
        }
        __syncthreads();

        v8s af[4][2], bf[4][2];
#pragma unroll
        for (int m = 0; m < 4; ++m) {
            int row = wr * 64 + m * 16 + lr;
#pragma unroll
            for (int kk = 0; kk < 2; ++kk) {
                int c = (kk * 64 + lg * 16) ^ ((row & 7) << 4);
                af[m][kk] = *reinterpret_cast<const v8s*>((const char*)sA + row * 128 + c);
            }
        }
#pragma unroll
        for (int n = 0; n < 4; ++n) {
            int row = wc * 64 + n * 16 + lr;
#pragma unroll
            for (int kk = 0; kk < 2; ++kk) {
                int c = (kk * 64 + lg * 16) ^ ((row & 7) << 4);
                bf[n][kk] = *reinterpret_cast<const v8s*>((const char*)sB + row * 128 + c);
            }
        }
#pragma unroll
        for (int m = 0; m < 4; ++m)
#pragma unroll
            for (int n = 0; n < 4; ++n) {
                acc[m][n] = MFMA(af[m][0], bf[n][0], acc[m][n]);
                acc[m][n] = MFMA(af[m][1], bf[n][1], acc[m][n]);
            }
    }

    // epilogue: C element (row=(lane>>4)*4+reg, col=lane&15) per m89-verified layout
#pragma unroll
    for (int m = 0; m < 4; ++m) {
        int rowb = m0 + wr * 64 + m * 16 + lg * 4;
#pragma unroll
        for (int n = 0; n < 4; ++n) {
            int gn = n0 + wc * 64 + n * 16 + lr;
            float bs = bias[gn];
            if (EPI == 0) {
                int which = gn >> 10, e = gn & 1023;
                int h = e >> 6, d = e & 63;
#pragma unroll
                for (int r = 0; r < 4; ++r) {
                    int grow = rowb + r;
                    int b = grow >> 11, t = grow & 2047;
                    size_t bh = (size_t)(b * 16 + h);
                    float v = acc[m][n][r] + bs;
                    if (which == 0)
                        outq[(bh * 2048 + t) * 64 + d] = f2bf(v * 0.125f);
                    else if (which == 1)
                        outk[(bh * 2048 + t) * 64 + d] = f2bf(v);
                    else
                        outv[(bh * 64 + d) * 2048 + t] = f2bf(v);
                }
            } else {
#pragma unroll
                for (int r = 0; r < 4; ++r)
                    outf[(size_t)(rowb + r) * 1024 + gn] = acc[m][n][r] + bs;
            }
        }
    }
}

// ---------------- flash attention (causal), hd=64, KVBLK=64, LDS-staged K/V ----------------
// qb/kb: [BH][T][64] bf16 (q pre-scaled by 0.125), vT: [BH][64][T] bf16; yb: [B][T][E] bf16
// 1D grid 2048; XCD-clustered + LPT. LDS = 40960 B exactly -> 4 blocks/CU (was 2: the round-8
// latency-bound diagnosis — MfmaUtil 9%, VALU 34%, Occ 22%, all idle — says TLP is the lever).
__global__ __launch_bounds__(256, 4) void attn_kernel(const unsigned short* __restrict__ qb,
                                                      const unsigned short* __restrict__ kb,
                                                      const unsigned short* __restrict__ vT,
                                                      unsigned short* __restrict__ yb) {
    __shared__ unsigned short sK[2][64 * 64];   // [kv][d], XOR-swizzled rows, dbuf (16 KB)
    __shared__ unsigned short sV[2][64 * 64];   // [d][kv], XOR-swizzled rows, dbuf (16 KB)
    __shared__ unsigned short pbuf[4][16 * 64]; // per-wave P tile, XOR-swizzled (8 KB)

    const int tid = threadIdx.x;
    const int lane = tid & 63, wid = tid >> 6;
    const int lr = lane & 15, lg = lane >> 4;

    // XCD-clustering swizzle (m157, bijective since 2048%8==0) + LPT qt order
    const int bid = blockIdx.x;
    const int o = (bid & 7) * 256 + (bid >> 3);
    const int bh = o >> 5;
    const int qt = 31 - (o & 31);

    const unsigned short* Q  = qb + (size_t)bh * 2048 * 64;
    const unsigned short* Kp = kb + (size_t)bh * 2048 * 64;
    const unsigned short* Vt = vT + (size_t)bh * 64 * 2048;

    const int q0 = qt * 64 + wid * 16;
    v8s qf0 = *reinterpret_cast<const v8s*>(Q + (size_t)(q0 + lr) * 64 + lg * 8);
    v8s qf1 = *reinterpret_cast<const v8s*>(Q + (size_t)(q0 + lr) * 64 + 32 + lg * 8);

    // staging geometry (rule 21): linear LDS dest + inverse-swizzled global source
    int strow[2], stcol[2];
#pragma unroll
    for (int it = 0; it < 2; ++it) {
        int os = it * 4096 + tid * 16;
        int row = os >> 7, cb = os & 127;
        strow[it] = row;
        stcol[it] = (cb ^ ((row & 7) << 4)) >> 1;
    }

    auto stage = [&](int buf, int kv0) {
#pragma unroll
        for (int it = 0; it < 2; ++it) {
            int os = it * 4096 + tid * 16;
            __builtin_amdgcn_global_load_lds(
                AS1(Kp + (size_t)(kv0 + strow[it]) * 64 + stcol[it]),
                AS3((char*)sK[buf] + os), 16, 0, 0);
            __builtin_amdgcn_global_load_lds(
                AS1(Vt + (size_t)strow[it] * 2048 + kv0 + stcol[it]),
                AS3((char*)sV[buf] + os), 16, 0, 0);
        }
    };

    float mrow[4], lrow[4];
    v4f yacc[4] = {};
#pragma unroll
    for (int r = 0; r < 4; ++r) { mrow[r] = -1e30f; lrow[r] = 0.f; }

    stage(0, 0);
    int cur = 0;
    for (int kt = 0; kt <= qt; ++kt) {
        __syncthreads();                       // buf[cur] staged (vmcnt drained at barrier)
        if (kt < qt) stage(cur ^ 1, (kt + 1) * 64);

        // QK^T: S[q=lg*4+r][kv=j*16+lr], K from swizzled LDS
        v4f sacc[4] = {};
#pragma unroll
        for (int j = 0; j < 4; ++j) {
            int row = j * 16 + lr;
            int sw = (row & 7) << 4;
            v8s kf0 = *reinterpret_cast<const v8s*>((const char*)sK[cur] + row * 128 + ((lg * 16) ^ sw));
            v8s kf1 = *reinterpret_cast<const v8s*>((const char*)sK[cur] + row * 128 + ((64 + lg * 16) ^ sw));
            sacc[j] = MFMA(qf0, kf0, sacc[j]);
            sacc[j] = MFMA(qf1, kf1, sacc[j]);
        }

        if (kt == qt) {                        // only the diagonal tile needs masking
            const int qrb = q0 + lg * 4;
            const int kv0 = kt * 64;
#pragma unroll
            for (int j = 0; j < 4; ++j) {
                int kv = kv0 + j * 16 + lr;
#pragma unroll
                for (int r = 0; r < 4; ++r)
                    if (kv > qrb + r) sacc[j][r] = -1e30f;
            }
        }

        // online softmax (reduce over kv: 4 regs + 16-lane shuffle group)
        float sc[4];
#pragma unroll
        for (int r = 0; r < 4; ++r) {
            float tmax = fmaxf(fmaxf(sacc[0][r], sacc[1][r]), fmaxf(sacc[2][r], sacc[3][r]));
#pragma unroll
            for (int off = 1; off < 16; off <<= 1)
                tmax = fmaxf(tmax, __shfl_xor(tmax, off, 64));
            float newm = fmaxf(mrow[r], tmax);
            sc[r] = __expf(mrow[r] - newm);
            mrow[r] = newm;
            float ps = 0.f;
#pragma unroll
            for (int j = 0; j < 4; ++j) {
                float p = __expf(sacc[j][r] - newm);
                sacc[j][r] = p;
                ps += p;
            }
#pragma unroll
            for (int off = 1; off < 16; off <<= 1)
                ps += __shfl_xor(ps, off, 64);
            lrow[r] = lrow[r] * sc[r] + ps;
        }
#pragma unroll
        for (int n = 0; n < 4; ++n)
#pragma unroll
            for (int r = 0; r < 4; ++r) yacc[n][r] *= sc[r];

        // P (16q x 64kv) -> per-wave LDS slice, stride 64 hw + XOR swizzle
        // write hw: q*64 + (col ^ ((q&7)<<3))  <->  read byte: q*128 + ((lg*16) ^ ((q&7)<<4))
        unsigned short* pw = pbuf[wid];
#pragma unroll
        for (int j = 0; j < 4; ++j) {
#pragma unroll
            for (int r = 0; r < 4; ++r) {
                int q = lg * 4 + r;
                pw[q * 64 + ((j * 16 + lr) ^ ((q & 7) << 3))] = f2bf(sacc[j][r]);
            }
        }

        const char* pb = (const char*)pbuf[wid];
        v8s pf0 = *reinterpret_cast<const v8s*>(pb + lr * 128 + ((lg * 16) ^ ((lr & 7) << 4)));
        v8s pf1 = *reinterpret_cast<const v8s*>(pb + lr * 128 + ((64 + lg * 16) ^ ((lr & 7) << 4)));
#pragma unroll
        for (int n = 0; n < 4; ++n) {
            int row = n * 16 + lr;
            int sw = (row & 7) << 4;
            v8s vf0 = *reinterpret_cast<const v8s*>((const char*)sV[cur] + row * 128 + ((lg * 16) ^ sw));
            v8s vf1 = *reinterpret_cast<const v8s*>((const char*)sV[cur] + row * 128 + ((64 + lg * 16) ^ sw));
            yacc[n] = MFMA(pf0, vf0, yacc[n]);
            yacc[n] = MFMA(pf1, vf1, yacc[n]);
        }
        cur ^= 1;
    }

    const int b = bh >> 4, h = bh & 15;
#pragma unroll
    for (int r = 0; r < 4; ++r) {
        float inv = 1.0f / lrow[r];
        int t = q0 + lg * 4 + r;
#pragma unroll
        for (int n = 0; n < 4; ++n)
            yb[((size_t)b * 2048 + t) * 1024 + h * 64 + n * 16 + lr] = f2bf(yacc[n][r] * inv);
    }
}

// ---------------- launch ----------------
extern "C" void kernel_launch(void* const* d_in, const int* in_sizes, int n_in,
                              void* d_out, int out_size, void* d_ws, size_t ws_size,
                              hipStream_t stream) {
    const float* x     = (const float*)d_in[0];
    const float* W_qkv = (const float*)d_in[1];
    const float* b_qkv = (const float*)d_in[2];
    const float* W_out = (const float*)d_in[3];
    const float* b_out = (const float*)d_in[4];
    float* out = (float*)d_out;

    if (ws_size < (72ull << 20)) return;   // clean fail instead of corruption

    char* ws = (char*)d_ws;
    unsigned short* xb_yb = (unsigned short*)(ws);                  // 16 MB (xb, then reused as yb)
    unsigned short* qbf   = (unsigned short*)(ws + (16ull << 20));  // 16 MB
    unsigned short* kbf   = (unsigned short*)(ws + (32ull << 20));  // 16 MB
    unsigned short* vTb   = (unsigned short*)(ws + (48ull << 20));  // 16 MB
    unsigned short* wqkvT = (unsigned short*)(ws + (64ull << 20));  // 6 MB
    unsigned short* woutT = (unsigned short*)(ws + (70ull << 20));  // 2 MB

    cast_x_kernel<<<dim3(4096), dim3(256), 0, stream>>>(x, xb_yb);
    transpose_w_kernel<<<dim3(96, 32), dim3(32, 8), 0, stream>>>(W_qkv, wqkvT, 1024, 3072);
    transpose_w_kernel<<<dim3(32, 32), dim3(32, 8), 0, stream>>>(W_out, woutT, 1024, 1024);
    gemm_bt<0><<<dim3(64, 24), dim3(256), 0, stream>>>(xb_yb, wqkvT, b_qkv, qbf, kbf, vTb, nullptr);
    attn_kernel<<<dim3(2048), dim3(256), 0, stream>>>(qbf, kbf, vTb, xb_yb);
    gemm_bt<1><<<dim3(64, 8), dim3(256), 0, stream>>>(xb_yb, woutT, b_out, nullptr, nullptr, nullptr, out);
}

// Round 10
// 274.634 us; speedup vs baseline: 2.3106x; 1.1626x over previous
//
#include <hip/hip_runtime.h>
#include <cstdint>
#include <cstddef>

// ---------------- types ----------------
using v8s  = __attribute__((ext_vector_type(8))) short;   // 8 x bf16 (4 VGPR)
using v4f  = __attribute__((ext_vector_type(4))) float;   // MFMA accumulator

#define MFMA(a, b, c) __builtin_amdgcn_mfma_f32_16x16x32_bf16(a, b, c, 0, 0, 0)
#define AS1(p) (const __attribute__((address_space(1))) void*)(p)
#define AS3(p) (__attribute__((address_space(3))) void*)(p)

__device__ __forceinline__ unsigned short f2bf(float f) {
    unsigned int u = __float_as_uint(f);
    unsigned int r = (u + 0x7fffu + ((u >> 16) & 1u)) >> 16;   // RNE, finite inputs
    return (unsigned short)r;
}

// ---------------- cast x -> bf16 ----------------
__global__ __launch_bounds__(256) void cast_x_kernel(const float* __restrict__ x,
                                                     unsigned short* __restrict__ xb) {
    size_t i = ((size_t)blockIdx.x * 256 + threadIdx.x) * 8;
    float4 a = *reinterpret_cast<const float4*>(x + i);
    float4 b = *reinterpret_cast<const float4*>(x + i + 4);
    union { unsigned short u[8]; v8s v; } o;
    o.u[0] = f2bf(a.x); o.u[1] = f2bf(a.y); o.u[2] = f2bf(a.z); o.u[3] = f2bf(a.w);
    o.u[4] = f2bf(b.x); o.u[5] = f2bf(b.y); o.u[6] = f2bf(b.z); o.u[7] = f2bf(b.w);
    *reinterpret_cast<v8s*>(xb + i) = o.v;
}

// ---------------- W [K][N] fp32 -> Wt [N][K] bf16 ----------------
__global__ __launch_bounds__(256) void transpose_w_kernel(const float* __restrict__ W,
                                                          unsigned short* __restrict__ Wt,
                                                          int Kd, int Nd) {
    __shared__ float tile[32][33];
    int tx = threadIdx.x, ty = threadIdx.y;
    int n0 = blockIdx.x * 32, k0 = blockIdx.y * 32;
#pragma unroll
    for (int i = 0; i < 4; ++i)
        tile[ty + i * 8][tx] = W[(size_t)(k0 + ty + i * 8) * Nd + (n0 + tx)];
    __syncthreads();
#pragma unroll
    for (int i = 0; i < 4; ++i)
        Wt[(size_t)(n0 + ty + i * 8) * Kd + (k0 + tx)] = f2bf(tile[tx][ty + i * 8]);
}

// ---------------- GEMM: C[M,N] = A[M,K=1024] * Bt[N,K=1024]^T ----------------
// EPI 0: qkv scatter epilogue (q scaled 0.125, v transposed), EPI 1: fp32 out + bias
template <int EPI>
__global__ __launch_bounds__(256, 3) void gemm_bt(const unsigned short* __restrict__ A,
                                                  const unsigned short* __restrict__ Bt,
                                                  const float* __restrict__ bias,
                                                  unsigned short* __restrict__ outq,
                                                  unsigned short* __restrict__ outk,
                                                  unsigned short* __restrict__ outv,
                                                  float* __restrict__ outf) {
    __shared__ unsigned short sA[128 * 64];
    __shared__ unsigned short sB[128 * 64];
    const int tid = threadIdx.x;
    const int lane = tid & 63, wid = tid >> 6;
    const int lr = lane & 15, lg = lane >> 4;
    const int m0 = blockIdx.x * 128, n0 = blockIdx.y * 128;
    const int wr = wid >> 1, wc = wid & 1;

    v4f acc[4][4] = {};

    int srow[4], scol[4];
#pragma unroll
    for (int j = 0; j < 4; ++j) {
        int o = j * 4096 + tid * 16;
        int row = o >> 7, cb = o & 127;
        srow[j] = row;
        scol[j] = (cb ^ ((row & 7) << 4)) >> 1;   // halfword offset within row
    }

    for (int kt = 0; kt < 16; ++kt) {
        __syncthreads();
#pragma unroll
        for (int j = 0; j < 4; ++j) {
            const unsigned short* ga = A + (size_t)(m0 + srow[j]) * 1024 + kt * 64 + scol[j];
            __builtin_amdgcn_global_load_lds(AS1(ga), AS3((char*)sA + j * 4096 + wid * 1024), 16, 0, 0);
            const unsigned short* gb = Bt + (size_t)(n0 + srow[j]) * 1024 + kt * 64 + scol[j];
            __builtin_amdgcn_global_load_lds(AS1(gb), AS3((char*)sB + j * 4096 + wid * 1024), 16, 0, 0);
        }
        __syncthreads();

        v8s af[4][2], bf[4][2];
#pragma unroll
        for (int m = 0; m < 4; ++m) {
            int row = wr * 64 + m * 16 + lr;
#pragma unroll
            for (int kk = 0; kk < 2; ++kk) {
                int c = (kk * 64 + lg * 16) ^ ((row & 7) << 4);
                af[m][kk] = *reinterpret_cast<const v8s*>((const char*)sA + row * 128 + c);
            }
        }
#pragma unroll
        for (int n = 0; n < 4; ++n) {
            int row = wc * 64 + n * 16 + lr;
#pragma unroll
            for (int kk = 0; kk < 2; ++kk) {
                int c = (kk * 64 + lg * 16) ^ ((row & 7) << 4);
                bf[n][kk] = *reinterpret_cast<const v8s*>((const char*)sB + row * 128 + c);
            }
        }
#pragma unroll
        for (int m = 0; m < 4; ++m)
#pragma unroll
            for (int n = 0; n < 4; ++n) {
                acc[m][n] = MFMA(af[m][0], bf[n][0], acc[m][n]);
                acc[m][n] = MFMA(af[m][1], bf[n][1], acc[m][n]);
            }
    }

    // epilogue: C element (row=(lane>>4)*4+reg, col=lane&15) per m89-verified layout
#pragma unroll
    for (int m = 0; m < 4; ++m) {
        int rowb = m0 + wr * 64 + m * 16 + lg * 4;
#pragma unroll
        for (int n = 0; n < 4; ++n) {
            int gn = n0 + wc * 64 + n * 16 + lr;
            float bs = bias[gn];
            if (EPI == 0) {
                int which = gn >> 10, e = gn & 1023;
                int h = e >> 6, d = e & 63;
#pragma unroll
                for (int r = 0; r < 4; ++r) {
                    int grow = rowb + r;
                    int b = grow >> 11, t = grow & 2047;
                    size_t bh = (size_t)(b * 16 + h);
                    float v = acc[m][n][r] + bs;
                    if (which == 0)
                        outq[(bh * 2048 + t) * 64 + d] = f2bf(v * 0.125f);
                    else if (which == 1)
                        outk[(bh * 2048 + t) * 64 + d] = f2bf(v);
                    else
                        outv[(bh * 64 + d) * 2048 + t] = f2bf(v);
                }
            } else {
#pragma unroll
                for (int r = 0; r < 4; ++r)
                    outf[(size_t)(rowb + r) * 1024 + gn] = acc[m][n][r] + bs;
            }
        }
    }
}

// ---------------- flash attention (causal), hd=64, KVBLK=64, swapped QK^T ----------------
// qb/kb: [BH][T][64] bf16 (q pre-scaled), vT: [BH][64][T] bf16; yb: [B][T][E] bf16
// Round-10 change: S^T = MFMA(K,Q) so each lane owns a full q-row of S (q=lane&15) ->
// softmax reduce = in-lane tree + 2 shfl_xor (was 32 ds_bpermute per tile, the serial chain).
__global__ __launch_bounds__(256, 4) void attn_kernel(const unsigned short* __restrict__ qb,
                                                      const unsigned short* __restrict__ kb,
                                                      const unsigned short* __restrict__ vT,
                                                      unsigned short* __restrict__ yb) {
    __shared__ unsigned short sK[2][64 * 64];   // [kv][d], XOR-swizzled rows, dbuf (16 KB)
    __shared__ unsigned short sV[2][64 * 64];   // [d][kv], XOR-swizzled rows, dbuf (16 KB)
    __shared__ unsigned short pbuf[4][16 * 64]; // per-wave P tile, XOR-swizzled (8 KB)

    const int tid = threadIdx.x;
    const int lane = tid & 63, wid = tid >> 6;
    const int lr = lane & 15, lg = lane >> 4;

    // XCD-clustering swizzle (bijective, 2048%8==0) + LPT qt order
    const int bid = blockIdx.x;
    const int o = (bid & 7) * 256 + (bid >> 3);
    const int bh = o >> 5;
    const int qt = 31 - (o & 31);

    const unsigned short* Q  = qb + (size_t)bh * 2048 * 64;
    const unsigned short* Kp = kb + (size_t)bh * 2048 * 64;
    const unsigned short* Vt = vT + (size_t)bh * 64 * 2048;

    const int q0 = qt * 64 + wid * 16;
    v8s qf0 = *reinterpret_cast<const v8s*>(Q + (size_t)(q0 + lr) * 64 + lg * 8);
    v8s qf1 = *reinterpret_cast<const v8s*>(Q + (size_t)(q0 + lr) * 64 + 32 + lg * 8);

    // staging geometry (rule 21): linear LDS dest + inverse-swizzled global source
    int strow[2], stcol[2];
#pragma unroll
    for (int it = 0; it < 2; ++it) {
        int os = it * 4096 + tid * 16;
        int row = os >> 7, cb = os & 127;
        strow[it] = row;
        stcol[it] = (cb ^ ((row & 7) << 4)) >> 1;
    }

    auto stage = [&](int buf, int kv0) {
#pragma unroll
        for (int it = 0; it < 2; ++it) {
            int os = it * 4096 + tid * 16;
            __builtin_amdgcn_global_load_lds(
                AS1(Kp + (size_t)(kv0 + strow[it]) * 64 + stcol[it]),
                AS3((char*)sK[buf] + os), 16, 0, 0);
            __builtin_amdgcn_global_load_lds(
                AS1(Vt + (size_t)strow[it] * 2048 + kv0 + stcol[it]),
                AS3((char*)sV[buf] + os), 16, 0, 0);
        }
    };

    float mrow = -1e30f, lrow = 0.f;   // running max/sum for q = q0 + lr (scalar per lane)
    v4f yacc[4] = {};

    stage(0, 0);
    int cur = 0;
    for (int kt = 0; kt <= qt; ++kt) {
        __syncthreads();                       // buf[cur] staged (vmcnt drained at barrier)
        if (kt < qt) stage(cur ^ 1, (kt + 1) * 64);

        // swapped QK^T: S^T[kv][q]; lane holds S[q=q0+lr][kv=kv0+16j+4*lg+r]
        v4f sacc[4] = {};
#pragma unroll
        for (int j = 0; j < 4; ++j) {
            int row = j * 16 + lr;
            int sw = (row & 7) << 4;
            v8s kf0 = *reinterpret_cast<const v8s*>((const char*)sK[cur] + row * 128 + ((lg * 16) ^ sw));
            v8s kf1 = *reinterpret_cast<const v8s*>((const char*)sK[cur] + row * 128 + ((64 + lg * 16) ^ sw));
            sacc[j] = MFMA(kf0, qf0, sacc[j]);
            sacc[j] = MFMA(kf1, qf1, sacc[j]);
        }

        if (kt == qt) {                        // only the diagonal tile needs masking
            const int qq = q0 + lr;
            const int kv0 = kt * 64;
#pragma unroll
            for (int j = 0; j < 4; ++j)
#pragma unroll
                for (int r = 0; r < 4; ++r)
                    if (kv0 + j * 16 + lg * 4 + r > qq) sacc[j][r] = -1e30f;
        }

        // online softmax: in-lane 16-value reduce + butterfly over 4 row-copies (lanes ^16,^32)
        float tmax = -1e30f;
#pragma unroll
        for (int j = 0; j < 4; ++j)
            tmax = fmaxf(tmax, fmaxf(fmaxf(sacc[j][0], sacc[j][1]), fmaxf(sacc[j][2], sacc[j][3])));
        tmax = fmaxf(tmax, __shfl_xor(tmax, 16, 64));
        tmax = fmaxf(tmax, __shfl_xor(tmax, 32, 64));
        float newm = fmaxf(mrow, tmax);
        float sc = __expf(mrow - newm);
        mrow = newm;
        float ps = 0.f;
#pragma unroll
        for (int j = 0; j < 4; ++j)
#pragma unroll
            for (int r = 0; r < 4; ++r) {
                float p = __expf(sacc[j][r] - newm);
                sacc[j][r] = p;
                ps += p;
            }
        ps += __shfl_xor(ps, 16, 64);
        ps += __shfl_xor(ps, 32, 64);
        lrow = lrow * sc + ps;

        // fetch rescale factors for yacc rows (q-local = 4*lg + r, held at lane 4*lg+r)
        float scq[4];
#pragma unroll
        for (int r = 0; r < 4; ++r) scq[r] = __shfl(sc, lg * 4 + r, 64);
#pragma unroll
        for (int n = 0; n < 4; ++n)
#pragma unroll
            for (int r = 0; r < 4; ++r) yacc[n][r] *= scq[r];

        // P -> per-wave LDS slice (swizzled, validated layout): row q=lr, col kv=16j+4lg+r.
        // adjacent kv pairs pack to one b32 (XOR keeps bit0: swizzle bits are >=3).
        unsigned short* pw = pbuf[wid];
#pragma unroll
        for (int j = 0; j < 4; ++j)
#pragma unroll
            for (int r = 0; r < 4; r += 2) {
                int c = j * 16 + lg * 4 + r;
                unsigned int pk = (unsigned int)f2bf(sacc[j][r]) |
                                  ((unsigned int)f2bf(sacc[j][r + 1]) << 16);
                *reinterpret_cast<unsigned int*>(&pw[lr * 64 + (c ^ ((lr & 7) << 3))]) = pk;
            }

        const char* pb = (const char*)pbuf[wid];
        v8s pf0 = *reinterpret_cast<const v8s*>(pb + lr * 128 + ((lg * 16) ^ ((lr & 7) << 4)));
        v8s pf1 = *reinterpret_cast<const v8s*>(pb + lr * 128 + ((64 + lg * 16) ^ ((lr & 7) << 4)));
#pragma unroll
        for (int n = 0; n < 4; ++n) {
            int row = n * 16 + lr;
            int sw = (row & 7) << 4;
            v8s vf0 = *reinterpret_cast<const v8s*>((const char*)sV[cur] + row * 128 + ((lg * 16) ^ sw));
            v8s vf1 = *reinterpret_cast<const v8s*>((const char*)sV[cur] + row * 128 + ((64 + lg * 16) ^ sw));
            yacc[n] = MFMA(pf0, vf0, yacc[n]);
            yacc[n] = MFMA(pf1, vf1, yacc[n]);
        }
        cur ^= 1;
    }

    // epilogue: fetch 1/l for yacc rows, write [B][T][E]
    float inv = 1.0f / lrow;
    float invq[4];
#pragma unroll
    for (int r = 0; r < 4; ++r) invq[r] = __shfl(inv, lg * 4 + r, 64);

    const int b = bh >> 4, h = bh & 15;
#pragma unroll
    for (int r = 0; r < 4; ++r) {
        int t = q0 + lg * 4 + r;
#pragma unroll
        for (int n = 0; n < 4; ++n)
            yb[((size_t)b * 2048 + t) * 1024 + h * 64 + n * 16 + lr] = f2bf(yacc[n][r] * invq[r]);
    }
}

// ---------------- launch ----------------
extern "C" void kernel_launch(void* const* d_in, const int* in_sizes, int n_in,
                              void* d_out, int out_size, void* d_ws, size_t ws_size,
                              hipStream_t stream) {
    const float* x     = (const float*)d_in[0];
    const float* W_qkv = (const float*)d_in[1];
    const float* b_qkv = (const float*)d_in[2];
    const float* W_out = (const float*)d_in[3];
    const float* b_out = (const float*)d_in[4];
    float* out = (float*)d_out;

    if (ws_size < (72ull << 20)) return;   // clean fail instead of corruption

    char* ws = (char*)d_ws;
    unsigned short* xb_yb = (unsigned short*)(ws);                  // 16 MB (xb, then reused as yb)
    unsigned short* qbf   = (unsigned short*)(ws + (16ull << 20));  // 16 MB
    unsigned short* kbf   = (unsigned short*)(ws + (32ull << 20));  // 16 MB
    unsigned short* vTb   = (unsigned short*)(ws + (48ull << 20));  // 16 MB
    unsigned short* wqkvT = (unsigned short*)(ws + (64ull << 20));  // 6 MB
    unsigned short* woutT = (unsigned short*)(ws + (70ull << 20));  // 2 MB

    cast_x_kernel<<<dim3(4096), dim3(256), 0, stream>>>(x, xb_yb);
    transpose_w_kernel<<<dim3(96, 32), dim3(32, 8), 0, stream>>>(W_qkv, wqkvT, 1024, 3072);
    transpose_w_kernel<<<dim3(32, 32), dim3(32, 8), 0, stream>>>(W_out, woutT, 1024, 1024);
    gemm_bt<0><<<dim3(64, 24), dim3(256), 0, stream>>>(xb_yb, wqkvT, b_qkv, qbf, kbf, vTb, nullptr);
    attn_kernel<<<dim3(2048), dim3(256), 0, stream>>>(qbf, kbf, vTb, xb_yb);
    gemm_bt<1><<<dim3(64, 8), dim3(256), 0, stream>>>(xb_yb, woutT, b_out, nullptr, nullptr, nullptr, out);
}

// Round 11
// 270.716 us; speedup vs baseline: 2.3441x; 1.0145x over previous
//
#include <hip/hip_runtime.h>
#include <cstdint>
#include <cstddef>

// ---------------- types ----------------
using v8s  = __attribute__((ext_vector_type(8))) short;   // 8 x bf16 (4 VGPR)
using v4f  = __attribute__((ext_vector_type(4))) float;   // MFMA accumulator

#define MFMA(a, b, c) __builtin_amdgcn_mfma_f32_16x16x32_bf16(a, b, c, 0, 0, 0)
#define AS1(p) (const __attribute__((address_space(1))) void*)(p)
#define AS3(p) (__attribute__((address_space(3))) void*)(p)

__device__ __forceinline__ unsigned short f2bf(float f) {
    unsigned int u = __float_as_uint(f);
    unsigned int r = (u + 0x7fffu + ((u >> 16) & 1u)) >> 16;   // RNE, finite inputs
    return (unsigned short)r;
}

// ---------------- cast x -> bf16 ----------------
__global__ __launch_bounds__(256) void cast_x_kernel(const float* __restrict__ x,
                                                     unsigned short* __restrict__ xb) {
    size_t i = ((size_t)blockIdx.x * 256 + threadIdx.x) * 8;
    float4 a = *reinterpret_cast<const float4*>(x + i);
    float4 b = *reinterpret_cast<const float4*>(x + i + 4);
    union { unsigned short u[8]; v8s v; } o;
    o.u[0] = f2bf(a.x); o.u[1] = f2bf(a.y); o.u[2] = f2bf(a.z); o.u[3] = f2bf(a.w);
    o.u[4] = f2bf(b.x); o.u[5] = f2bf(b.y); o.u[6] = f2bf(b.z); o.u[7] = f2bf(b.w);
    *reinterpret_cast<v8s*>(xb + i) = o.v;
}

// ---------------- W [K][N] fp32 -> Wt [N][K] bf16 ----------------
__global__ __launch_bounds__(256) void transpose_w_kernel(const float* __restrict__ W,
                                                          unsigned short* __restrict__ Wt,
                                                          int Kd, int Nd) {
    __shared__ float tile[32][33];
    int tx = threadIdx.x, ty = threadIdx.y;
    int n0 = blockIdx.x * 32, k0 = blockIdx.y * 32;
#pragma unroll
    for (int i = 0; i < 4; ++i)
        tile[ty + i * 8][tx] = W[(size_t)(k0 + ty + i * 8) * Nd + (n0 + tx)];
    __syncthreads();
#pragma unroll
    for (int i = 0; i < 4; ++i)
        Wt[(size_t)(n0 + ty + i * 8) * Kd + (k0 + tx)] = f2bf(tile[tx][ty + i * 8]);
}

// ---------------- GEMM: C[M,N] = A[M,K=1024] * Bt[N,K=1024]^T ----------------
// EPI 0: qkv scatter epilogue (q scaled 0.125, v transposed), EPI 1: fp32 out + bias
template <int EPI>
__global__ __launch_bounds__(256, 3) void gemm_bt(const unsigned short* __restrict__ A,
                                                  const unsigned short* __restrict__ Bt,
                                                  const float* __restrict__ bias,
                                                  unsigned short* __restrict__ outq,
                                                  unsigned short* __restrict__ outk,
                                                  unsigned short* __restrict__ outv,
                                                  float* __restrict__ outf) {
    __shared__ unsigned short sA[128 * 64];
    __shared__ unsigned short sB[128 * 64];
    const int tid = threadIdx.x;
    const int lane = tid & 63, wid = tid >> 6;
    const int lr = lane & 15, lg = lane >> 4;
    const int m0 = blockIdx.x * 128, n0 = blockIdx.y * 128;
    const int wr = wid >> 1, wc = wid & 1;

    v4f acc[4][4] = {};

    int srow[4], scol[4];
#pragma unroll
    for (int j = 0; j < 4; ++j) {
        int o = j * 4096 + tid * 16;
        int row = o >> 7, cb = o & 127;
        srow[j] = row;
        scol[j] = (cb ^ ((row & 7) << 4)) >> 1;   // halfword offset within row
    }

    for (int kt = 0; kt < 16; ++kt) {
        __syncthreads();
#pragma unroll
        for (int j = 0; j < 4; ++j) {
            const unsigned short* ga = A + (size_t)(m0 + srow[j]) * 1024 + kt * 64 + scol[j];
            __builtin_amdgcn_global_load_lds(AS1(ga), AS3((char*)sA + j * 4096 + wid * 1024), 16, 0, 0);
            const unsigned short* gb = Bt + (size_t)(n0 + srow[j]) * 1024 + kt * 64 + scol[j];
            __builtin_amdgcn_global_load_lds(AS1(gb), AS3((char*)sB + j * 4096 + wid * 1024), 16, 0, 0);
        }
        __syncthreads();

        v8s af[4][2], bf[4][2];
#pragma unroll
        for (int m = 0; m < 4; ++m) {
            int row = wr * 64 + m * 16 + lr;
#pragma unroll
            for (int kk = 0; kk < 2; ++kk) {
                int c = (kk * 64 + lg * 16) ^ ((row & 7) << 4);
                af[m][kk] = *reinterpret_cast<const v8s*>((const char*)sA + row * 128 + c);
            }
        }
#pragma unroll
        for (int n = 0; n < 4; ++n) {
            int row = wc * 64 + n * 16 + lr;
#pragma unroll
            for (int kk = 0; kk < 2; ++kk) {
                int c = (kk * 64 + lg * 16) ^ ((row & 7) << 4);
                bf[n][kk] = *reinterpret_cast<const v8s*>((const char*)sB + row * 128 + c);
            }
        }
#pragma unroll
        for (int m = 0; m < 4; ++m)
#pragma unroll
            for (int n = 0; n < 4; ++n) {
                acc[m][n] = MFMA(af[m][0], bf[n][0], acc[m][n]);
                acc[m][n] = MFMA(af[m][1], bf[n][1], acc[m][n]);
            }
    }

    // epilogue: C element (row=(lane>>4)*4+reg, col=lane&15) per m89-verified layout
#pragma unroll
    for (int m = 0; m < 4; ++m) {
        int rowb = m0 + wr * 64 + m * 16 + lg * 4;
#pragma unroll
        for (int n = 0; n < 4; ++n) {
            int gn = n0 + wc * 64 + n * 16 + lr;
            float bs = bias[gn];
            if (EPI == 0) {
                int which = gn >> 10, e = gn & 1023;
                int h = e >> 6, d = e & 63;
#pragma unroll
                for (int r = 0; r < 4; ++r) {
                    int grow = rowb + r;
                    int b = grow >> 11, t = grow & 2047;
                    size_t bh = (size_t)(b * 16 + h);
                    float v = acc[m][n][r] + bs;
                    if (which == 0)
                        outq[(bh * 2048 + t) * 64 + d] = f2bf(v * 0.125f);
                    else if (which == 1)
                        outk[(bh * 2048 + t) * 64 + d] = f2bf(v);
                    else
                        outv[(bh * 64 + d) * 2048 + t] = f2bf(v);
                }
            } else {
#pragma unroll
                for (int r = 0; r < 4; ++r)
                    outf[(size_t)(rowb + r) * 1024 + gn] = acc[m][n][r] + bs;
            }
        }
    }
}

// ---------------- flash attention (causal), hd=64, KVBLK=64, QBLK=128, 8 waves ----------------
// qb/kb: [BH][T][64] bf16 (q pre-scaled), vT: [BH][64][T] bf16; yb: [B][T][E] bf16
// Round-11: QBLK 64->128 (512 thr) — staged K/V tile feeds 2x q rows (staging/barriers per
// q-row halved; the measured 39% neither-pipe idle), P-pack via v_cvt_pk_bf16_f32 (T12).
__global__ __launch_bounds__(512, 6) void attn_kernel(const unsigned short* __restrict__ qb,
                                                      const unsigned short* __restrict__ kb,
                                                      const unsigned short* __restrict__ vT,
                                                      unsigned short* __restrict__ yb) {
    __shared__ unsigned short sK[2][64 * 64];   // [kv][d], XOR-swizzled rows, dbuf (16 KB)
    __shared__ unsigned short sV[2][64 * 64];   // [d][kv], XOR-swizzled rows, dbuf (16 KB)
    __shared__ unsigned short pbuf[8][16 * 64]; // per-wave P tile, XOR-swizzled (16 KB)

    const int tid = threadIdx.x;
    const int lane = tid & 63, wid = tid >> 6;
    const int lr = lane & 15, lg = lane >> 4;

    // XCD-clustering swizzle (bijective, 1024%8==0) + LPT qt order (16 q-tiles of 128)
    const int bid = blockIdx.x;
    const int o = (bid & 7) * 128 + (bid >> 3);
    const int bh = o >> 4;
    const int qt = 15 - (o & 15);

    const unsigned short* Q  = qb + (size_t)bh * 2048 * 64;
    const unsigned short* Kp = kb + (size_t)bh * 2048 * 64;
    const unsigned short* Vt = vT + (size_t)bh * 64 * 2048;

    const int q0 = qt * 128 + wid * 16;
    v8s qf0 = *reinterpret_cast<const v8s*>(Q + (size_t)(q0 + lr) * 64 + lg * 8);
    v8s qf1 = *reinterpret_cast<const v8s*>(Q + (size_t)(q0 + lr) * 64 + 32 + lg * 8);

    // staging (rule 21): 512 thr x 16B covers one 8KB tile in a single iteration
    const int sos   = tid * 16;
    const int strow = sos >> 7;
    const int stcol = ((sos & 127) ^ ((strow & 7) << 4)) >> 1;

    auto stage = [&](int buf, int kv0) {
        __builtin_amdgcn_global_load_lds(
            AS1(Kp + (size_t)(kv0 + strow) * 64 + stcol),
            AS3((char*)sK[buf] + sos), 16, 0, 0);
        __builtin_amdgcn_global_load_lds(
            AS1(Vt + (size_t)strow * 2048 + kv0 + stcol),
            AS3((char*)sV[buf] + sos), 16, 0, 0);
    };

    float mrow = -1e30f, lrow = 0.f;   // running max/sum for q = q0 + lr (scalar per lane)
    v4f yacc[4] = {};

    const int ntiles = 2 * qt + 2;
    stage(0, 0);
    int cur = 0;
    for (int kt = 0; kt < ntiles; ++kt) {
        __syncthreads();                       // buf[cur] staged (vmcnt drained at barrier)
        if (kt + 1 < ntiles) stage(cur ^ 1, (kt + 1) * 64);

        // swapped QK^T: S^T[kv][q]; lane holds S[q=q0+lr][kv=kv0+16j+4*lg+r]
        v4f sacc[4] = {};
#pragma unroll
        for (int j = 0; j < 4; ++j) {
            int row = j * 16 + lr;
            int sw = (row & 7) << 4;
            v8s kf0 = *reinterpret_cast<const v8s*>((const char*)sK[cur] + row * 128 + ((lg * 16) ^ sw));
            v8s kf1 = *reinterpret_cast<const v8s*>((const char*)sK[cur] + row * 128 + ((64 + lg * 16) ^ sw));
            sacc[j] = MFMA(kf0, qf0, sacc[j]);
            sacc[j] = MFMA(kf1, qf1, sacc[j]);
        }

        const int kv0 = kt * 64;
        if (kv0 + 63 > q0) {                   // this wave's diagonal (or beyond) tile
            const int qq = q0 + lr;
#pragma unroll
            for (int j = 0; j < 4; ++j)
#pragma unroll
                for (int r = 0; r < 4; ++r)
                    if (kv0 + j * 16 + lg * 4 + r > qq) sacc[j][r] = -1e30f;
        }

        // online softmax: in-lane 16-value reduce + butterfly over 4 row-copies (lanes ^16,^32)
        float tmax = -1e30f;
#pragma unroll
        for (int j = 0; j < 4; ++j)
            tmax = fmaxf(tmax, fmaxf(fmaxf(sacc[j][0], sacc[j][1]), fmaxf(sacc[j][2], sacc[j][3])));
        tmax = fmaxf(tmax, __shfl_xor(tmax, 16, 64));
        tmax = fmaxf(tmax, __shfl_xor(tmax, 32, 64));
        float newm = fmaxf(mrow, tmax);
        float sc = __expf(mrow - newm);
        mrow = newm;
        float ps = 0.f;
#pragma unroll
        for (int j = 0; j < 4; ++j)
#pragma unroll
            for (int r = 0; r < 4; ++r) {
                float p = __expf(sacc[j][r] - newm);
                sacc[j][r] = p;
                ps += p;
            }
        ps += __shfl_xor(ps, 16, 64);
        ps += __shfl_xor(ps, 32, 64);
        lrow = lrow * sc + ps;

        // fetch rescale factors for yacc rows (q-local = 4*lg + r, held at lane 4*lg+r)
        float scq[4];
#pragma unroll
        for (int r = 0; r < 4; ++r) scq[r] = __shfl(sc, lg * 4 + r, 64);
#pragma unroll
        for (int n = 0; n < 4; ++n)
#pragma unroll
            for (int r = 0; r < 4; ++r) yacc[n][r] *= scq[r];

        // P -> per-wave LDS slice (validated swizzle): row q=lr, col kv=16j+4lg+r.
        // pack kv pairs with v_cvt_pk_bf16_f32 (T12 recipe; no builtin on gfx950).
        unsigned short* pw = pbuf[wid];
#pragma unroll
        for (int j = 0; j < 4; ++j)
#pragma unroll
            for (int r = 0; r < 4; r += 2) {
                int c = j * 16 + lg * 4 + r;
                unsigned int pk;
                asm("v_cvt_pk_bf16_f32 %0, %1, %2"
                    : "=v"(pk) : "v"(sacc[j][r]), "v"(sacc[j][r + 1]));
                *reinterpret_cast<unsigned int*>(&pw[lr * 64 + (c ^ ((lr & 7) << 3))]) = pk;
            }

        const char* pb = (const char*)pbuf[wid];
        v8s pf0 = *reinterpret_cast<const v8s*>(pb + lr * 128 + ((lg * 16) ^ ((lr & 7) << 4)));
        v8s pf1 = *reinterpret_cast<const v8s*>(pb + lr * 128 + ((64 + lg * 16) ^ ((lr & 7) << 4)));
#pragma unroll
        for (int n = 0; n < 4; ++n) {
            int row = n * 16 + lr;
            int sw = (row & 7) << 4;
            v8s vf0 = *reinterpret_cast<const v8s*>((const char*)sV[cur] + row * 128 + ((lg * 16) ^ sw));
            v8s vf1 = *reinterpret_cast<const v8s*>((const char*)sV[cur] + row * 128 + ((64 + lg * 16) ^ sw));
            yacc[n] = MFMA(pf0, vf0, yacc[n]);
            yacc[n] = MFMA(pf1, vf1, yacc[n]);
        }
        cur ^= 1;
    }

    // epilogue: fetch 1/l for yacc rows, write [B][T][E]
    float inv = 1.0f / lrow;
    float invq[4];
#pragma unroll
    for (int r = 0; r < 4; ++r) invq[r] = __shfl(inv, lg * 4 + r, 64);

    const int b = bh >> 4, h = bh & 15;
#pragma unroll
    for (int r = 0; r < 4; ++r) {
        int t = q0 + lg * 4 + r;
#pragma unroll
        for (int n = 0; n < 4; ++n)
            yb[((size_t)b * 2048 + t) * 1024 + h * 64 + n * 16 + lr] = f2bf(yacc[n][r] * invq[r]);
    }
}

// ---------------- launch ----------------
extern "C" void kernel_launch(void* const* d_in, const int* in_sizes, int n_in,
                              void* d_out, int out_size, void* d_ws, size_t ws_size,
                              hipStream_t stream) {
    const float* x     = (const float*)d_in[0];
    const float* W_qkv = (const float*)d_in[1];
    const float* b_qkv = (const float*)d_in[2];
    const float* W_out = (const float*)d_in[3];
    const float* b_out = (const float*)d_in[4];
    float* out = (float*)d_out;

    if (ws_size < (72ull << 20)) return;   // clean fail instead of corruption

    char* ws = (char*)d_ws;
    unsigned short* xb_yb = (unsigned short*)(ws);                  // 16 MB (xb, then reused as yb)
    unsigned short* qbf   = (unsigned short*)(ws + (16ull << 20));  // 16 MB
    unsigned short* kbf   = (unsigned short*)(ws + (32ull << 20));  // 16 MB
    unsigned short* vTb   = (unsigned short*)(ws + (48ull << 20));  // 16 MB
    unsigned short* wqkvT = (unsigned short*)(ws + (64ull << 20));  // 6 MB
    unsigned short* woutT = (unsigned short*)(ws + (70ull << 20));  // 2 MB

    cast_x_kernel<<<dim3(4096), dim3(256), 0, stream>>>(x, xb_yb);
    transpose_w_kernel<<<dim3(96, 32), dim3(32, 8), 0, stream>>>(W_qkv, wqkvT, 1024, 3072);
    transpose_w_kernel<<<dim3(32, 32), dim3(32, 8), 0, stream>>>(W_out, woutT, 1024, 1024);
    gemm_bt<0><<<dim3(64, 24), dim3(256), 0, stream>>>(xb_yb, wqkvT, b_qkv, qbf, kbf, vTb, nullptr);
    attn_kernel<<<dim3(1024), dim3(512), 0, stream>>>(qbf, kbf, vTb, xb_yb);
    gemm_bt<1><<<dim3(64, 8), dim3(256), 0, stream>>>(xb_yb, woutT, b_out, nullptr, nullptr, nullptr, out);
}